// Round 6
// baseline (579.006 us; speedup 1.0000x reference)
//
#include <hip/hip_runtime.h>

#define U_   8
#define B_   16384
#define NC_  62

typedef __attribute__((ext_vector_type(8))) short bfrag;   // 8 bf16 (4 VGPRs)
typedef __attribute__((ext_vector_type(4))) float facc;    // 4 fp32 acc

__device__ __forceinline__ float bf2f(unsigned int lo16) {
    union { unsigned int i; float f; } v;
    v.i = lo16 << 16;
    return v.f;
}
__device__ __forceinline__ unsigned short f2bf(float f) {
    unsigned int x = __float_as_uint(f);
    return (unsigned short)((x + 0x7fffu + ((x >> 16) & 1u)) >> 16);
}
__device__ __forceinline__ void gl2lds16(const void* g, void* l) {
    __builtin_amdgcn_global_load_lds(
        (const __attribute__((address_space(1))) void*)g,
        (__attribute__((address_space(3))) void*)l, 16, 0, 0);
}

// ---------------------------------------------------------------------------
// prep: normalized policies, final per-unit weights, folded output bias
// ---------------------------------------------------------------------------
__global__ void prep_kernel(const float* __restrict__ p1, const float* __restrict__ p2,
                            const float* __restrict__ pf, const float* __restrict__ b2,
                            float* __restrict__ P1n, float* __restrict__ P2n,
                            float* __restrict__ wfin, float* __restrict__ cconst)
{
    int t = threadIdx.x;
    if (t >= 64) return;
    int row = t >> 3;
    float s1 = 0.f, s2 = 0.f;
    for (int f = 0; f < 8; f++) { s1 += p1[row * 8 + f]; s2 += p2[row * 8 + f]; }
    P1n[t] = p1[t] * (s1 > 0.f ? 1.f / s1 : 1.f);
    P2n[t] = p2[t] * (s2 > 0.f ? 1.f / s2 : 1.f);
    float d = 0.f;
    for (int j = 0; j < 8; j++) d += pf[j];
    float inv = d > 0.f ? 1.f / d : 1.f;
    float wv[8];
    for (int j = 0; j < 8; j++) {
        float v = pf[j];
        for (int i = j; i < 8; i++) v *= inv;   // inv applied (8-j) times
        wv[j] = v;
    }
    if (t < 8) wfin[t] = wv[t];
    float cc = 0.f;
    if (t < NC_) for (int u = 0; u < 8; u++) cc += wv[u] * b2[u * NC_ + t];
    cconst[t] = cc;
}

// ---------------------------------------------------------------------------
// reorder_w0: W0 [u][k=512][n=512] fp32 -> W0r[n'][k] bf16,
//             n' = (n>>5)*256 + u*32 + (n&31)   (256-col groups: 8u x 32f)
// ---------------------------------------------------------------------------
__global__ __launch_bounds__(256) void reorder_w0(
    const float* __restrict__ W0, unsigned short* __restrict__ W0r)
{
    __shared__ float tile[32][33];
    const int u  = blockIdx.z;
    const int n0 = blockIdx.x * 32, k0 = blockIdx.y * 32;
    const int tx = threadIdx.x & 31, ty = threadIdx.x >> 5;
    const float* Wb = W0 + (long)u * 512 * 512;
#pragma unroll
    for (int i = 0; i < 4; i++)
        tile[ty + i * 8][tx] = Wb[(long)(k0 + ty + i * 8) * 512 + n0 + tx];
    __syncthreads();
#pragma unroll
    for (int i = 0; i < 4; i++) {
        int n = n0 + ty + i * 8, k = k0 + tx;
        int np = (n >> 5) * 256 + u * 32 + (n & 31);
        W0r[(long)np * 512 + k] = f2bf(tile[tx][ty + i * 8]);
    }
}

// ---------------------------------------------------------------------------
// transpose_w: W [u][k=512][n=512] fp32 -> Wt [u][n][k] bf16
// ---------------------------------------------------------------------------
__global__ __launch_bounds__(256) void transpose_w(
    const float* __restrict__ W, unsigned short* __restrict__ Wt)
{
    __shared__ float tile[32][33];
    const int u  = blockIdx.z;
    const int n0 = blockIdx.x * 32, k0 = blockIdx.y * 32;
    const int tx = threadIdx.x & 31, ty = threadIdx.x >> 5;
    const float* Wb = W + (long)u * 512 * 512;
#pragma unroll
    for (int i = 0; i < 4; i++)
        tile[ty + i * 8][tx] = Wb[(long)(k0 + ty + i * 8) * 512 + n0 + tx];
    __syncthreads();
    unsigned short* Wo = Wt + (long)u * 512 * 512;
#pragma unroll
    for (int i = 0; i < 4; i++) {
        int n = n0 + ty + i * 8, k = k0 + tx;
        Wo[(long)n * 512 + k] = f2bf(tile[tx][ty + i * 8]);
    }
}

// ---------------------------------------------------------------------------
// wout_build: Woutt[c][f*512+k] = sum_u wfin[u]*P2n[u,f]*W2[u][k][c]  (c<62)
// ---------------------------------------------------------------------------
__global__ __launch_bounds__(256) void wout_build(
    const float* __restrict__ W2, const float* __restrict__ P2n,
    const float* __restrict__ wfin, unsigned short* __restrict__ Woutt)
{
    const int c   = threadIdx.x & 63;
    const int row = blockIdx.x * 4 + (threadIdx.x >> 6);   // [0,4096)
    const int f = row >> 9, k = row & 511;
    float s = 0.f;
    if (c < NC_) {
#pragma unroll
        for (int u = 0; u < 8; u++)
            s += wfin[u] * P2n[u * 8 + f] * W2[((long)u * 512 + k) * NC_ + c];
    }
    Woutt[(long)c * 4096 + row] = f2bf(s);
}

// ---------------------------------------------------------------------------
// x fp32 -> bf16, 8 elems/thread
// ---------------------------------------------------------------------------
__global__ __launch_bounds__(256) void convert_x(
    const float* __restrict__ x, unsigned short* __restrict__ xb, long n)
{
    long i = ((long)blockIdx.x * 256 + threadIdx.x) * 8;
    if (i >= n) return;
    const float4* xp = (const float4*)(x + i);
    float4 a = xp[0], b = xp[1];
    uint4 o;
    o.x = f2bf(a.x) | ((unsigned)f2bf(a.y) << 16);
    o.y = f2bf(a.z) | ((unsigned)f2bf(a.w) << 16);
    o.z = f2bf(b.x) | ((unsigned)f2bf(b.y) << 16);
    o.w = f2bf(b.z) | ((unsigned)f2bf(b.w) << 16);
    *(uint4*)(xb + i) = o;
}

// ---------------------------------------------------------------------------
// gemm0_mix (unchanged from R4): 512 threads, 128 rows x 256 cols, BK=64,
// xor-swizzled LDS, LDS mix epilogue, planar a1 with 64-B-run stores.
// ---------------------------------------------------------------------------
__global__ __launch_bounds__(512, 4) void gemm0_mix(
    const unsigned short* __restrict__ xb, const unsigned short* __restrict__ W0r,
    const float* __restrict__ b0, const float* __restrict__ P1n,
    unsigned short* __restrict__ a1, long plane)
{
    __shared__ __align__(16) unsigned short sm[128 * 264];   // 67584 B
    unsigned short* sA = sm;              // [128 rows][64] slab, xor-swizzled
    unsigned short* sB = sm + 128 * 64;   // [256 n][64]
    const int tid = threadIdx.x, w = tid >> 6, lane = tid & 63;
    const int flat = blockIdx.x;
    const int xcd = flat & 7, seq = flat >> 3;
    const int ng = xcd * 2 + (seq & 1);           // 2 n-groups per XCD
    const long mBase = (long)(seq >> 1) * 128;

    const int lr = lane >> 3;                 // row within 8-row chunk
    const int lg = (lane & 7) ^ lr;           // xor-swizzled source granule
    const int wm = w >> 2, wn = w & 3;
    const int r = lane & 15, q = lane >> 4;
    const int x7 = r & 7;

    facc acc[4][4];
#pragma unroll
    for (int i = 0; i < 4; i++)
#pragma unroll
        for (int j = 0; j < 4; j++) acc[i][j] = (facc){0.f, 0.f, 0.f, 0.f};

    for (int k0 = 0; k0 < 512; k0 += 64) {
        __syncthreads();
#pragma unroll
        for (int i = 0; i < 2; i++) {
            const int c = w + i * 8;
            gl2lds16(xb + (mBase + c * 8 + lr) * 512 + k0 + lg * 8, sA + c * 512);
        }
#pragma unroll
        for (int i = 0; i < 4; i++) {
            const int c = w * 4 + i;
            gl2lds16(W0r + ((long)ng * 256 + c * 8 + lr) * 512 + k0 + lg * 8,
                     sB + c * 512);
        }
        __syncthreads();
#pragma unroll
        for (int h = 0; h < 2; h++) {
            const int xg = ((h * 4 + q) ^ x7) * 8;
            bfrag aF[4], bF[4];
#pragma unroll
            for (int mt = 0; mt < 4; mt++)
                aF[mt] = *(const bfrag*)&sA[(wm * 64 + mt * 16 + r) * 64 + xg];
#pragma unroll
            for (int nt = 0; nt < 4; nt++)
                bF[nt] = *(const bfrag*)&sB[(wn * 64 + nt * 16 + r) * 64 + xg];
#pragma unroll
            for (int mt = 0; mt < 4; mt++)
#pragma unroll
                for (int nt = 0; nt < 4; nt++)
                    acc[mt][nt] = __builtin_amdgcn_mfma_f32_16x16x32_bf16(
                        aF[mt], bF[nt], acc[mt][nt], 0, 0, 0);
        }
    }

    __syncthreads();   // reuse sm as h0 tile [128 rows][264]
#pragma unroll
    for (int nt = 0; nt < 4; nt++) {
        const int cl = wn * 64 + nt * 16 + r;      // u = cl>>5, f = cl&31
        const float bv = b0[(cl >> 5) * 512 + ng * 32 + (cl & 31)];
#pragma unroll
        for (int mt = 0; mt < 4; mt++) {
            const int rowb = wm * 64 + mt * 16 + q * 4;
#pragma unroll
            for (int rg = 0; rg < 4; rg++) {
                float v = acc[mt][nt][rg] + bv;
                v = v > 0.f ? v : 0.f;
                sm[(rowb + rg) * 264 + cl] = f2bf(v);
            }
        }
    }
    __syncthreads();

    float pw[64];
#pragma unroll
    for (int i = 0; i < 64; i++) pw[i] = P1n[i];   // uniform -> SGPRs
    const int row = tid >> 2, fs = (tid & 3) * 8;
    float hv[8][8];
#pragma unroll
    for (int u = 0; u < 8; u++) {
        bfrag hx = *(const bfrag*)&sm[row * 264 + u * 32 + fs];
#pragma unroll
        for (int j = 0; j < 8; j++)
            hv[u][j] = bf2f((unsigned int)(unsigned short)hx[j]);
    }
    const long rowOff = (mBase + row) * 512 + ng * 32 + fs;
#pragma unroll
    for (int t = 0; t < 8; t++) {
        float o[8];
#pragma unroll
        for (int j = 0; j < 8; j++) {
            float s = 0.f;
#pragma unroll
            for (int u = 0; u < 8; u++) s = fmaf(pw[t * 8 + u], hv[u][j], s);
            o[j] = s;
        }
        uint4 ov;
        ov.x = f2bf(o[0]) | ((unsigned)f2bf(o[1]) << 16);
        ov.y = f2bf(o[2]) | ((unsigned)f2bf(o[3]) << 16);
        ov.z = f2bf(o[4]) | ((unsigned)f2bf(o[5]) << 16);
        ov.w = f2bf(o[6]) | ((unsigned)f2bf(o[7]) << 16);
        *(uint4*)(a1 + (long)t * plane + rowOff) = ov;
    }
}

// ---------------------------------------------------------------------------
// gemm_h_out v2: block = (u, 128-row tile). Loop nb=0..3:
//   stage 1: h1 tile 128x128 = relu(a1[u]@W1t[u]+b1)   [R4 gemm_h tile shape]
//   stage 2: out-partial 128x64 += h1_tile @ Woutt slice (through xor-slab LDS)
// Weight bytes per row identical to unfused R4 gemm_h. h1 never hits HBM.
// Partial plane per u; reduced 8-way afterwards.
// ---------------------------------------------------------------------------
__global__ __launch_bounds__(256, 3) void gemm_h_out(
    const unsigned short* __restrict__ a1,     // planar [u][rows][512]
    const unsigned short* __restrict__ W1t,    // [u][n=512][k=512]
    const float* __restrict__ b1,
    const unsigned short* __restrict__ Woutt,  // [c=64][u*512+k]
    float* __restrict__ partial, long plane, int Bc)
{
    __shared__ __align__(16) unsigned short sm[16384];   // 32 KB
    unsigned short* sA = sm;             // [128][64]
    unsigned short* sB = sm + 8192;      // [128][64]
    unsigned short* sH = sm;             // overlay: [2 slabs][128][64]

    const int tid = threadIdx.x, w = tid >> 6, lane = tid & 63;
    const int flat = blockIdx.x;
    const int u = flat & 7;                     // consecutive blocks -> diff u
    const long mBase = (long)(flat >> 3) * 128;

    const int lr = lane >> 3, lg = (lane & 7) ^ lr;
    const int wm = w >> 1, wn = w & 1;
    const int r = lane & 15, q = lane >> 4;
    const int x7 = r & 7;

    const unsigned short* Ab = a1 + (long)u * plane;

    facc acc2[2][4];                            // out tile: rows w*32+mt*16, cols nt*16
#pragma unroll
    for (int i = 0; i < 2; i++)
#pragma unroll
        for (int j = 0; j < 4; j++) acc2[i][j] = (facc){0.f, 0.f, 0.f, 0.f};

    for (int nb = 0; nb < 4; nb++) {
        const int nBase = nb * 128;

        // ---- stage 1: 128x128 h1 tile, K=512 (R4 gemm_h structure)
        facc acc1[4][4];
#pragma unroll
        for (int i = 0; i < 4; i++)
#pragma unroll
            for (int j = 0; j < 4; j++) acc1[i][j] = (facc){0.f, 0.f, 0.f, 0.f};

        for (int k0 = 0; k0 < 512; k0 += 64) {
            __syncthreads();
#pragma unroll
            for (int i = 0; i < 4; i++) {
                const int c = w * 4 + i;
                gl2lds16(Ab + (mBase + c * 8 + lr) * 512 + k0 + lg * 8, sA + c * 512);
                gl2lds16(W1t + ((long)u * 512 + nBase + c * 8 + lr) * 512 + k0 + lg * 8,
                         sB + c * 512);
            }
            __syncthreads();
#pragma unroll
            for (int h = 0; h < 2; h++) {
                const int xg = ((h * 4 + q) ^ x7) * 8;
                bfrag aF[4], bF[4];
#pragma unroll
                for (int mt = 0; mt < 4; mt++)
                    aF[mt] = *(const bfrag*)&sA[(wm * 64 + mt * 16 + r) * 64 + xg];
#pragma unroll
                for (int nt = 0; nt < 4; nt++)
                    bF[nt] = *(const bfrag*)&sB[(wn * 64 + nt * 16 + r) * 64 + xg];
#pragma unroll
                for (int mt = 0; mt < 4; mt++)
#pragma unroll
                    for (int nt = 0; nt < 4; nt++)
                        acc1[mt][nt] = __builtin_amdgcn_mfma_f32_16x16x32_bf16(
                            aF[mt], bF[nt], acc1[mt][nt], 0, 0, 0);
            }
        }

        __syncthreads();   // sA/sB reads done everywhere before sH overlay

        // epilogue: relu+bias -> sH xor-slab ([slab=col>>6][row][xor granule])
#pragma unroll
        for (int nt = 0; nt < 4; nt++) {
            const int col = wn * 64 + nt * 16 + r;      // [0,128)
            const float bv = b1[u * 512 + nBase + col];
            const int slab = col >> 6, cg = (col >> 3) & 7, ce = col & 7;
#pragma unroll
            for (int mt = 0; mt < 4; mt++) {
                const int rowb = wm * 64 + mt * 16 + q * 4;
#pragma unroll
                for (int rg = 0; rg < 4; rg++) {
                    const int row = rowb + rg;
                    float v = acc1[mt][nt][rg] + bv;
                    v = v > 0.f ? v : 0.f;
                    sH[slab * 8192 + row * 64 + ((cg ^ (row & 7)) * 8) + ce] = f2bf(v);
                }
            }
        }
        __syncthreads();

        // ---- stage 2: acc2 += h1_tile(128x128) @ Woutt[u][nBase..+128][c]
#pragma unroll
        for (int ks = 0; ks < 4; ks++) {
            const int kh = ks >> 1, h2 = ks & 1;
            bfrag aF2[2], bF2[4];
#pragma unroll
            for (int mt = 0; mt < 2; mt++) {
                const int row = w * 32 + mt * 16 + r;   // row&7 == r&7 == x7
                aF2[mt] = *(const bfrag*)&sH[kh * 8192 + row * 64
                                             + (((h2 * 4 + q) ^ x7) * 8)];
            }
#pragma unroll
            for (int nt = 0; nt < 4; nt++) {
                const int c = nt * 16 + r;
                bF2[nt] = *(const bfrag*)(Woutt + (long)c * 4096 + u * 512
                                          + nBase + ks * 32 + q * 8);
            }
#pragma unroll
            for (int mt = 0; mt < 2; mt++)
#pragma unroll
                for (int nt = 0; nt < 4; nt++)
                    acc2[mt][nt] = __builtin_amdgcn_mfma_f32_16x16x32_bf16(
                        aF2[mt], bF2[nt], acc2[mt][nt], 0, 0, 0);
        }
        // next nb's k-loop top barrier protects sH before sA/sB overwrite
    }

    // write fp32 partial plane for this u (64-B runs)
    float* pb = partial + ((long)u * Bc + mBase) * 64;
#pragma unroll
    for (int nt = 0; nt < 4; nt++) {
        const int col = nt * 16 + r;
#pragma unroll
        for (int mt = 0; mt < 2; mt++) {
#pragma unroll
            for (int rg = 0; rg < 4; rg++) {
                const int row = w * 32 + mt * 16 + q * 4 + rg;
                pb[(long)row * 64 + col] = acc2[mt][nt][rg];
            }
        }
    }
}

// ---------------------------------------------------------------------------
// reduce_out: out[row][c] = sum_{u<8} partial[u][row][c] + cconst[c]
// ---------------------------------------------------------------------------
__global__ __launch_bounds__(256) void reduce_out(
    const float* __restrict__ partial, const float* __restrict__ cconst,
    float* __restrict__ out, int Bc)
{
    const long flat = (long)blockIdx.x * 256 + threadIdx.x;
    const long row = flat >> 2;
    const int cg = (int)(flat & 3) * 16;
    float s[16];
#pragma unroll
    for (int j = 0; j < 16; j++) s[j] = 0.f;
#pragma unroll
    for (int u = 0; u < 8; u++) {
        const float4* p = (const float4*)(partial + ((long)u * Bc + row) * 64 + cg);
#pragma unroll
        for (int v4 = 0; v4 < 4; v4++) {
            float4 v = p[v4];
            s[v4 * 4 + 0] += v.x; s[v4 * 4 + 1] += v.y;
            s[v4 * 4 + 2] += v.z; s[v4 * 4 + 3] += v.w;
        }
    }
#pragma unroll
    for (int j = 0; j < 16; j++) {
        const int c = cg + j;
        if (c < NC_) out[row * NC_ + c] = s[j] + cconst[c];
    }
}

// ---------------------------------------------------------------------------
extern "C" void kernel_launch(void* const* d_in, const int* in_sizes, int n_in,
                              void* d_out, int out_size, void* d_ws, size_t ws_size,
                              hipStream_t stream)
{
    const float* x  = (const float*)d_in[0];
    const float* p1 = (const float*)d_in[1];
    const float* p2 = (const float*)d_in[2];
    const float* pf = (const float*)d_in[3];
    const float* W0 = (const float*)d_in[4];
    const float* b0 = (const float*)d_in[5];
    const float* W1 = (const float*)d_in[6];
    const float* b1 = (const float*)d_in[7];
    const float* W2 = (const float*)d_in[8];
    const float* b2 = (const float*)d_in[9];
    float* out = (float*)d_out;

    char* ws = (char*)d_ws;
    size_t off = 0;
    auto alloc = [&](size_t bytes) -> void* {
        void* p = ws + off;
        off += (bytes + 255) & ~(size_t)255;
        return p;
    };
    float* P1n    = (float*)alloc(64 * sizeof(float));
    float* P2n    = (float*)alloc(64 * sizeof(float));
    float* wfin   = (float*)alloc(8 * sizeof(float));
    float* cconst = (float*)alloc(64 * sizeof(float));
    unsigned short* W0r   = (unsigned short*)alloc((size_t)4096 * 512 * 2);
    unsigned short* W1t   = (unsigned short*)alloc((size_t)U_ * 512 * 512 * 2);
    unsigned short* Woutt = (unsigned short*)alloc((size_t)64 * 4096 * 2);
    unsigned short* xb    = (unsigned short*)alloc((size_t)B_ * 512 * 2);

    // a1 planar (8 planes x Bc x 512 bf16) + fp32 partial (8 x Bc x 64)
    size_t remain = ws_size > off ? ws_size - off : 0;
    int Bc = 2048;
    for (int cand = B_; cand >= 2048; cand >>= 1) {
        size_t need = 8ull * cand * 512 * 2 + 8ull * cand * 64 * 4 + 1024;
        if (need <= remain) { Bc = cand; break; }
    }
    unsigned short* a1 = (unsigned short*)alloc(8ull * Bc * 512 * 2);
    float* partial     = (float*)alloc(8ull * Bc * 64 * 4);

    prep_kernel<<<1, 64, 0, stream>>>(p1, p2, pf, b2, P1n, P2n, wfin, cconst);
    reorder_w0<<<dim3(16, 16, 8), 256, 0, stream>>>(W0, W0r);
    transpose_w<<<dim3(16, 16, 8), 256, 0, stream>>>(W1, W1t);
    wout_build<<<dim3(1024), 256, 0, stream>>>(W2, P2n, wfin, Woutt);
    convert_x<<<dim3(B_ * 512 / 8 / 256), 256, 0, stream>>>(x, xb, (long)B_ * 512);

    const int Mb = Bc / 128;
    const long plane = (long)Bc * 512;
    for (int bb = 0; bb < B_; bb += Bc) {
        gemm0_mix<<<dim3(16 * Mb), 512, 0, stream>>>(
            xb + (long)bb * 512, W0r, b0, P1n, a1, plane);
        gemm_h_out<<<dim3(8 * Mb), 256, 0, stream>>>(
            a1, W1t, b1, Woutt, partial, plane, Bc);
        reduce_out<<<dim3(Bc / 64), 256, 0, stream>>>(
            partial, cconst, out + (long)bb * NC_, Bc);
    }
}

// Round 7
// 340.975 us; speedup vs baseline: 1.6981x; 1.6981x over previous
//
#include <hip/hip_runtime.h>

#define U_   8
#define B_   16384
#define NC_  62

typedef __attribute__((ext_vector_type(8))) short bfrag;   // 8 bf16 (4 VGPRs)
typedef __attribute__((ext_vector_type(4))) float facc;    // 4 fp32 acc

__device__ __forceinline__ float bf2f(unsigned int lo16) {
    union { unsigned int i; float f; } v;
    v.i = lo16 << 16;
    return v.f;
}
__device__ __forceinline__ unsigned short f2bf(float f) {
    unsigned int x = __float_as_uint(f);
    return (unsigned short)((x + 0x7fffu + ((x >> 16) & 1u)) >> 16);
}
__device__ __forceinline__ void gl2lds16(const void* g, void* l) {
    __builtin_amdgcn_global_load_lds(
        (const __attribute__((address_space(1))) void*)g,
        (__attribute__((address_space(3))) void*)l, 16, 0, 0);
}

// ---------------------------------------------------------------------------
// prep: normalized policies, final per-unit weights, folded output bias
// ---------------------------------------------------------------------------
__global__ void prep_kernel(const float* __restrict__ p1, const float* __restrict__ p2,
                            const float* __restrict__ pf, const float* __restrict__ b2,
                            float* __restrict__ P1n, float* __restrict__ P2n,
                            float* __restrict__ wfin, float* __restrict__ cconst)
{
    int t = threadIdx.x;
    if (t >= 64) return;
    int row = t >> 3;
    float s1 = 0.f, s2 = 0.f;
    for (int f = 0; f < 8; f++) { s1 += p1[row * 8 + f]; s2 += p2[row * 8 + f]; }
    P1n[t] = p1[t] * (s1 > 0.f ? 1.f / s1 : 1.f);
    P2n[t] = p2[t] * (s2 > 0.f ? 1.f / s2 : 1.f);
    float d = 0.f;
    for (int j = 0; j < 8; j++) d += pf[j];
    float inv = d > 0.f ? 1.f / d : 1.f;
    float wv[8];
    for (int j = 0; j < 8; j++) {
        float v = pf[j];
        for (int i = j; i < 8; i++) v *= inv;   // inv applied (8-j) times
        wv[j] = v;
    }
    if (t < 8) wfin[t] = wv[t];
    float cc = 0.f;
    if (t < NC_) for (int u = 0; u < 8; u++) cc += wv[u] * b2[u * NC_ + t];
    cconst[t] = cc;
}

// ---------------------------------------------------------------------------
// reorder_w0: W0 [u][k=512][n=512] fp32 -> W0r[n'][k] bf16,
//             n' = (n>>5)*256 + u*32 + (n&31)   (256-col groups: 8u x 32f)
// ---------------------------------------------------------------------------
__global__ __launch_bounds__(256) void reorder_w0(
    const float* __restrict__ W0, unsigned short* __restrict__ W0r)
{
    __shared__ float tile[32][33];
    const int u  = blockIdx.z;
    const int n0 = blockIdx.x * 32, k0 = blockIdx.y * 32;
    const int tx = threadIdx.x & 31, ty = threadIdx.x >> 5;
    const float* Wb = W0 + (long)u * 512 * 512;
#pragma unroll
    for (int i = 0; i < 4; i++)
        tile[ty + i * 8][tx] = Wb[(long)(k0 + ty + i * 8) * 512 + n0 + tx];
    __syncthreads();
#pragma unroll
    for (int i = 0; i < 4; i++) {
        int n = n0 + ty + i * 8, k = k0 + tx;
        int np = (n >> 5) * 256 + u * 32 + (n & 31);
        W0r[(long)np * 512 + k] = f2bf(tile[tx][ty + i * 8]);
    }
}

// ---------------------------------------------------------------------------
// transpose_w: W [u][k=512][n=512] fp32 -> Wt [u][n][k] bf16
// ---------------------------------------------------------------------------
__global__ __launch_bounds__(256) void transpose_w(
    const float* __restrict__ W, unsigned short* __restrict__ Wt)
{
    __shared__ float tile[32][33];
    const int u  = blockIdx.z;
    const int n0 = blockIdx.x * 32, k0 = blockIdx.y * 32;
    const int tx = threadIdx.x & 31, ty = threadIdx.x >> 5;
    const float* Wb = W + (long)u * 512 * 512;
#pragma unroll
    for (int i = 0; i < 4; i++)
        tile[ty + i * 8][tx] = Wb[(long)(k0 + ty + i * 8) * 512 + n0 + tx];
    __syncthreads();
    unsigned short* Wo = Wt + (long)u * 512 * 512;
#pragma unroll
    for (int i = 0; i < 4; i++) {
        int n = n0 + ty + i * 8, k = k0 + tx;
        Wo[(long)n * 512 + k] = f2bf(tile[tx][ty + i * 8]);
    }
}

// ---------------------------------------------------------------------------
// wout_build: Woutt[c][f*512+k] = sum_u wfin[u]*P2n[u,f]*W2[u][k][c]  (c<62)
// ---------------------------------------------------------------------------
__global__ __launch_bounds__(256) void wout_build(
    const float* __restrict__ W2, const float* __restrict__ P2n,
    const float* __restrict__ wfin, unsigned short* __restrict__ Woutt)
{
    const int c   = threadIdx.x & 63;
    const int row = blockIdx.x * 4 + (threadIdx.x >> 6);   // [0,4096)
    const int f = row >> 9, k = row & 511;
    float s = 0.f;
    if (c < NC_) {
#pragma unroll
        for (int u = 0; u < 8; u++)
            s += wfin[u] * P2n[u * 8 + f] * W2[((long)u * 512 + k) * NC_ + c];
    }
    Woutt[(long)c * 4096 + row] = f2bf(s);
}

// ---------------------------------------------------------------------------
// x fp32 -> bf16, 8 elems/thread
// ---------------------------------------------------------------------------
__global__ __launch_bounds__(256) void convert_x(
    const float* __restrict__ x, unsigned short* __restrict__ xb, long n)
{
    long i = ((long)blockIdx.x * 256 + threadIdx.x) * 8;
    if (i >= n) return;
    const float4* xp = (const float4*)(x + i);
    float4 a = xp[0], b = xp[1];
    uint4 o;
    o.x = f2bf(a.x) | ((unsigned)f2bf(a.y) << 16);
    o.y = f2bf(a.z) | ((unsigned)f2bf(a.w) << 16);
    o.z = f2bf(b.x) | ((unsigned)f2bf(b.y) << 16);
    o.w = f2bf(b.z) | ((unsigned)f2bf(b.w) << 16);
    *(uint4*)(xb + i) = o;
}

// ---------------------------------------------------------------------------
// gemm0_mix (unchanged from R4): 512 threads, 128 rows x 256 cols, BK=64,
// xor-swizzled LDS, LDS mix epilogue, planar a1 with 64-B-run stores.
// ---------------------------------------------------------------------------
__global__ __launch_bounds__(512, 4) void gemm0_mix(
    const unsigned short* __restrict__ xb, const unsigned short* __restrict__ W0r,
    const float* __restrict__ b0, const float* __restrict__ P1n,
    unsigned short* __restrict__ a1, long plane)
{
    __shared__ __align__(16) unsigned short sm[128 * 264];   // 67584 B
    unsigned short* sA = sm;              // [128 rows][64] slab, xor-swizzled
    unsigned short* sB = sm + 128 * 64;   // [256 n][64]
    const int tid = threadIdx.x, w = tid >> 6, lane = tid & 63;
    const int flat = blockIdx.x;
    const int xcd = flat & 7, seq = flat >> 3;
    const int ng = xcd * 2 + (seq & 1);           // 2 n-groups per XCD
    const long mBase = (long)(seq >> 1) * 128;

    const int lr = lane >> 3;                 // row within 8-row chunk
    const int lg = (lane & 7) ^ lr;           // xor-swizzled source granule
    const int wm = w >> 2, wn = w & 3;
    const int r = lane & 15, q = lane >> 4;
    const int x7 = r & 7;

    facc acc[4][4];
#pragma unroll
    for (int i = 0; i < 4; i++)
#pragma unroll
        for (int j = 0; j < 4; j++) acc[i][j] = (facc){0.f, 0.f, 0.f, 0.f};

    for (int k0 = 0; k0 < 512; k0 += 64) {
        __syncthreads();
#pragma unroll
        for (int i = 0; i < 2; i++) {
            const int c = w + i * 8;
            gl2lds16(xb + (mBase + c * 8 + lr) * 512 + k0 + lg * 8, sA + c * 512);
        }
#pragma unroll
        for (int i = 0; i < 4; i++) {
            const int c = w * 4 + i;
            gl2lds16(W0r + ((long)ng * 256 + c * 8 + lr) * 512 + k0 + lg * 8,
                     sB + c * 512);
        }
        __syncthreads();
#pragma unroll
        for (int h = 0; h < 2; h++) {
            const int xg = ((h * 4 + q) ^ x7) * 8;
            bfrag aF[4], bF[4];
#pragma unroll
            for (int mt = 0; mt < 4; mt++)
                aF[mt] = *(const bfrag*)&sA[(wm * 64 + mt * 16 + r) * 64 + xg];
#pragma unroll
            for (int nt = 0; nt < 4; nt++)
                bF[nt] = *(const bfrag*)&sB[(wn * 64 + nt * 16 + r) * 64 + xg];
#pragma unroll
            for (int mt = 0; mt < 4; mt++)
#pragma unroll
                for (int nt = 0; nt < 4; nt++)
                    acc[mt][nt] = __builtin_amdgcn_mfma_f32_16x16x32_bf16(
                        aF[mt], bF[nt], acc[mt][nt], 0, 0, 0);
        }
    }

    __syncthreads();   // reuse sm as h0 tile [128 rows][264]
#pragma unroll
    for (int nt = 0; nt < 4; nt++) {
        const int cl = wn * 64 + nt * 16 + r;      // u = cl>>5, f = cl&31
        const float bv = b0[(cl >> 5) * 512 + ng * 32 + (cl & 31)];
#pragma unroll
        for (int mt = 0; mt < 4; mt++) {
            const int rowb = wm * 64 + mt * 16 + q * 4;
#pragma unroll
            for (int rg = 0; rg < 4; rg++) {
                float v = acc[mt][nt][rg] + bv;
                v = v > 0.f ? v : 0.f;
                sm[(rowb + rg) * 264 + cl] = f2bf(v);
            }
        }
    }
    __syncthreads();

    float pw[64];
#pragma unroll
    for (int i = 0; i < 64; i++) pw[i] = P1n[i];   // uniform -> SGPRs
    const int row = tid >> 2, fs = (tid & 3) * 8;
    float hv[8][8];
#pragma unroll
    for (int u = 0; u < 8; u++) {
        bfrag hx = *(const bfrag*)&sm[row * 264 + u * 32 + fs];
#pragma unroll
        for (int j = 0; j < 8; j++)
            hv[u][j] = bf2f((unsigned int)(unsigned short)hx[j]);
    }
    const long rowOff = (mBase + row) * 512 + ng * 32 + fs;
#pragma unroll
    for (int t = 0; t < 8; t++) {
        float o[8];
#pragma unroll
        for (int j = 0; j < 8; j++) {
            float s = 0.f;
#pragma unroll
            for (int u = 0; u < 8; u++) s = fmaf(pw[t * 8 + u], hv[u][j], s);
            o[j] = s;
        }
        uint4 ov;
        ov.x = f2bf(o[0]) | ((unsigned)f2bf(o[1]) << 16);
        ov.y = f2bf(o[2]) | ((unsigned)f2bf(o[3]) << 16);
        ov.z = f2bf(o[4]) | ((unsigned)f2bf(o[5]) << 16);
        ov.w = f2bf(o[6]) | ((unsigned)f2bf(o[7]) << 16);
        *(uint4*)(a1 + (long)t * plane + rowOff) = ov;
    }
}

// ---------------------------------------------------------------------------
// gemm_h_out v3: R4 gemm_h grid shape (block = u, nb, 128-row m-tile; A read
// ONCE per block). Stage 1: 128x128 h1 tile = relu(a1[u]@W1t[u]+b1), K=512.
// Stage 2 (fused epilogue): LDS xor-slab round-trip, 32 MFMA vs Woutt k-slice
// [u*512+nb*128 .. +128], write 128x64 fp32 partial plane p = u*4+nb.
// h1 never touches HBM; no gemm_out dispatch.
// ---------------------------------------------------------------------------
__global__ __launch_bounds__(256, 3) void gemm_h_out(
    const unsigned short* __restrict__ a1,     // planar [u][rows][512]
    const unsigned short* __restrict__ W1t,    // [u][n=512][k=512]
    const float* __restrict__ b1,
    const unsigned short* __restrict__ Woutt,  // [c=64][u*512+k]
    float* __restrict__ partial, long plane, int Bc)
{
    __shared__ __align__(16) unsigned short sm[16384];   // 32 KB
    unsigned short* sA = sm;             // [128][64]
    unsigned short* sB = sm + 8192;      // [128][64]
    unsigned short* sH = sm;             // overlay: [2 slabs][128][64]

    const int tid = threadIdx.x, w = tid >> 6, lane = tid & 63;
    const int flat = blockIdx.x;
    const int u = flat & 7;                     // consecutive blocks -> diff XCD/u
    const int nb = (flat >> 3) & 3;
    const long mBase = (long)(flat >> 5) * 128;
    const int nBase = nb * 128;

    const int lr = lane >> 3, lg = (lane & 7) ^ lr;
    const int wm = w >> 1, wn = w & 1;
    const int r = lane & 15, q = lane >> 4;
    const int x7 = r & 7;

    const unsigned short* Ab = a1 + (long)u * plane;

    // ---- stage 1: 128x128 h1 tile, K=512 (R4 gemm_h structure, A read once)
    facc acc1[4][4];
#pragma unroll
    for (int i = 0; i < 4; i++)
#pragma unroll
        for (int j = 0; j < 4; j++) acc1[i][j] = (facc){0.f, 0.f, 0.f, 0.f};

    for (int k0 = 0; k0 < 512; k0 += 64) {
        __syncthreads();
#pragma unroll
        for (int i = 0; i < 4; i++) {
            const int c = w * 4 + i;
            gl2lds16(Ab + (mBase + c * 8 + lr) * 512 + k0 + lg * 8, sA + c * 512);
            gl2lds16(W1t + ((long)u * 512 + nBase + c * 8 + lr) * 512 + k0 + lg * 8,
                     sB + c * 512);
        }
        __syncthreads();
#pragma unroll
        for (int h = 0; h < 2; h++) {
            const int xg = ((h * 4 + q) ^ x7) * 8;
            bfrag aF[4], bF[4];
#pragma unroll
            for (int mt = 0; mt < 4; mt++)
                aF[mt] = *(const bfrag*)&sA[(wm * 64 + mt * 16 + r) * 64 + xg];
#pragma unroll
            for (int nt = 0; nt < 4; nt++)
                bF[nt] = *(const bfrag*)&sB[(wn * 64 + nt * 16 + r) * 64 + xg];
#pragma unroll
            for (int mt = 0; mt < 4; mt++)
#pragma unroll
                for (int nt = 0; nt < 4; nt++)
                    acc1[mt][nt] = __builtin_amdgcn_mfma_f32_16x16x32_bf16(
                        aF[mt], bF[nt], acc1[mt][nt], 0, 0, 0);
        }
    }

    __syncthreads();   // sA/sB reads done everywhere before sH overlay

    // epilogue: relu+bias -> sH xor-slab ([slab=col>>6][row][xor granule])
#pragma unroll
    for (int nt = 0; nt < 4; nt++) {
        const int col = wn * 64 + nt * 16 + r;      // [0,128)
        const float bv = b1[u * 512 + nBase + col];
        const int slab = col >> 6, cg = (col >> 3) & 7, ce = col & 7;
#pragma unroll
        for (int mt = 0; mt < 4; mt++) {
            const int rowb = wm * 64 + mt * 16 + q * 4;
#pragma unroll
            for (int rg = 0; rg < 4; rg++) {
                const int row = rowb + rg;
                float v = acc1[mt][nt][rg] + bv;
                v = v > 0.f ? v : 0.f;
                sH[slab * 8192 + row * 64 + ((cg ^ (row & 7)) * 8) + ce] = f2bf(v);
            }
        }
    }
    __syncthreads();

    // ---- stage 2: partial = h1_tile(128x128) @ Woutt[u][nBase..+128][c]
    facc acc2[2][4];
#pragma unroll
    for (int i = 0; i < 2; i++)
#pragma unroll
        for (int j = 0; j < 4; j++) acc2[i][j] = (facc){0.f, 0.f, 0.f, 0.f};

#pragma unroll
    for (int ks = 0; ks < 4; ks++) {
        const int kh = ks >> 1, h2 = ks & 1;
        bfrag aF2[2], bF2[4];
#pragma unroll
        for (int mt = 0; mt < 2; mt++) {
            const int row = w * 32 + mt * 16 + r;   // row&7 == r&7 == x7
            aF2[mt] = *(const bfrag*)&sH[kh * 8192 + row * 64
                                         + (((h2 * 4 + q) ^ x7) * 8)];
        }
#pragma unroll
        for (int nt = 0; nt < 4; nt++) {
            const int c = nt * 16 + r;
            bF2[nt] = *(const bfrag*)(Woutt + (long)c * 4096 + u * 512
                                      + nBase + ks * 32 + q * 8);
        }
#pragma unroll
        for (int mt = 0; mt < 2; mt++)
#pragma unroll
            for (int nt = 0; nt < 4; nt++)
                acc2[mt][nt] = __builtin_amdgcn_mfma_f32_16x16x32_bf16(
                    aF2[mt], bF2[nt], acc2[mt][nt], 0, 0, 0);
    }

    // write fp32 partial plane p = u*4+nb (64-B runs)
    float* pb = partial + (((long)(u * 4 + nb)) * Bc + mBase) * 64;
#pragma unroll
    for (int nt = 0; nt < 4; nt++) {
        const int col = nt * 16 + r;
#pragma unroll
        for (int mt = 0; mt < 2; mt++) {
#pragma unroll
            for (int rg = 0; rg < 4; rg++) {
                const int row = w * 32 + mt * 16 + q * 4 + rg;
                pb[(long)row * 64 + col] = acc2[mt][nt][rg];
            }
        }
    }
}

// ---------------------------------------------------------------------------
// reduce_out: out[row][c] = sum_{p<32} partial[p][row][c] + cconst[c]
// ---------------------------------------------------------------------------
__global__ __launch_bounds__(256) void reduce_out(
    const float* __restrict__ partial, const float* __restrict__ cconst,
    float* __restrict__ out, int Bc)
{
    const long flat = (long)blockIdx.x * 256 + threadIdx.x;
    const long row = flat >> 2;
    const int cg = (int)(flat & 3) * 16;
    float s[16];
#pragma unroll
    for (int j = 0; j < 16; j++) s[j] = 0.f;
    for (int p = 0; p < 32; p++) {
        const float4* pp = (const float4*)(partial + ((long)p * Bc + row) * 64 + cg);
#pragma unroll
        for (int v4 = 0; v4 < 4; v4++) {
            float4 v = pp[v4];
            s[v4 * 4 + 0] += v.x; s[v4 * 4 + 1] += v.y;
            s[v4 * 4 + 2] += v.z; s[v4 * 4 + 3] += v.w;
        }
    }
#pragma unroll
    for (int j = 0; j < 16; j++) {
        const int c = cg + j;
        if (c < NC_) out[row * NC_ + c] = s[j] + cconst[c];
    }
}

// ---------------------------------------------------------------------------
extern "C" void kernel_launch(void* const* d_in, const int* in_sizes, int n_in,
                              void* d_out, int out_size, void* d_ws, size_t ws_size,
                              hipStream_t stream)
{
    const float* x  = (const float*)d_in[0];
    const float* p1 = (const float*)d_in[1];
    const float* p2 = (const float*)d_in[2];
    const float* pf = (const float*)d_in[3];
    const float* W0 = (const float*)d_in[4];
    const float* b0 = (const float*)d_in[5];
    const float* W1 = (const float*)d_in[6];
    const float* b1 = (const float*)d_in[7];
    const float* W2 = (const float*)d_in[8];
    const float* b2 = (const float*)d_in[9];
    float* out = (float*)d_out;

    char* ws = (char*)d_ws;
    size_t off = 0;
    auto alloc = [&](size_t bytes) -> void* {
        void* p = ws + off;
        off += (bytes + 255) & ~(size_t)255;
        return p;
    };
    float* P1n    = (float*)alloc(64 * sizeof(float));
    float* P2n    = (float*)alloc(64 * sizeof(float));
    float* wfin   = (float*)alloc(8 * sizeof(float));
    float* cconst = (float*)alloc(64 * sizeof(float));
    unsigned short* W0r   = (unsigned short*)alloc((size_t)4096 * 512 * 2);
    unsigned short* W1t   = (unsigned short*)alloc((size_t)U_ * 512 * 512 * 2);
    unsigned short* Woutt = (unsigned short*)alloc((size_t)64 * 4096 * 2);
    unsigned short* xb    = (unsigned short*)alloc((size_t)B_ * 512 * 2);

    // a1 planar (8 x Bc x 512 bf16) + fp32 partial (32 planes x Bc x 64)
    size_t remain = ws_size > off ? ws_size - off : 0;
    int Bc = 2048;
    for (int cand = B_; cand >= 2048; cand >>= 1) {
        size_t need = 8ull * cand * 512 * 2 + 32ull * cand * 64 * 4 + 1024;
        if (need <= remain) { Bc = cand; break; }
    }
    unsigned short* a1 = (unsigned short*)alloc(8ull * Bc * 512 * 2);
    float* partial     = (float*)alloc(32ull * Bc * 64 * 4);

    prep_kernel<<<1, 64, 0, stream>>>(p1, p2, pf, b2, P1n, P2n, wfin, cconst);
    reorder_w0<<<dim3(16, 16, 8), 256, 0, stream>>>(W0, W0r);
    transpose_w<<<dim3(16, 16, 8), 256, 0, stream>>>(W1, W1t);
    wout_build<<<dim3(1024), 256, 0, stream>>>(W2, P2n, wfin, Woutt);
    convert_x<<<dim3(B_ * 512 / 8 / 256), 256, 0, stream>>>(x, xb, (long)B_ * 512);

    const int Mb = Bc / 128;
    const long plane = (long)Bc * 512;
    for (int bb = 0; bb < B_; bb += Bc) {
        gemm0_mix<<<dim3(16 * Mb), 512, 0, stream>>>(
            xb + (long)bb * 512, W0r, b0, P1n, a1, plane);
        gemm_h_out<<<dim3(32 * Mb), 256, 0, stream>>>(
            a1, W1t, b1, Woutt, partial, plane, Bc);
        reduce_out<<<dim3(Bc / 64), 256, 0, stream>>>(
            partial, cconst, out + (long)bb * NC_, Bc);
    }
}

// Round 8
// 339.018 us; speedup vs baseline: 1.7079x; 1.0058x over previous
//
#include <hip/hip_runtime.h>

#define U_   8
#define B_   16384
#define NC_  62

typedef __attribute__((ext_vector_type(8))) short bfrag;   // 8 bf16 (4 VGPRs)
typedef __attribute__((ext_vector_type(4))) float facc;    // 4 fp32 acc

__device__ __forceinline__ float bf2f(unsigned int lo16) {
    union { unsigned int i; float f; } v;
    v.i = lo16 << 16;
    return v.f;
}
__device__ __forceinline__ unsigned short f2bf(float f) {
    unsigned int x = __float_as_uint(f);
    return (unsigned short)((x + 0x7fffu + ((x >> 16) & 1u)) >> 16);
}
__device__ __forceinline__ void gl2lds16(const void* g, void* l) {
    __builtin_amdgcn_global_load_lds(
        (const __attribute__((address_space(1))) void*)g,
        (__attribute__((address_space(3))) void*)l, 16, 0, 0);
}

// ---------------------------------------------------------------------------
// prep: normalized policies, final per-unit weights, folded output bias
// ---------------------------------------------------------------------------
__global__ void prep_kernel(const float* __restrict__ p1, const float* __restrict__ p2,
                            const float* __restrict__ pf, const float* __restrict__ b2,
                            float* __restrict__ P1n, float* __restrict__ P2n,
                            float* __restrict__ wfin, float* __restrict__ cconst)
{
    int t = threadIdx.x;
    if (t >= 64) return;
    int row = t >> 3;
    float s1 = 0.f, s2 = 0.f;
    for (int f = 0; f < 8; f++) { s1 += p1[row * 8 + f]; s2 += p2[row * 8 + f]; }
    P1n[t] = p1[t] * (s1 > 0.f ? 1.f / s1 : 1.f);
    P2n[t] = p2[t] * (s2 > 0.f ? 1.f / s2 : 1.f);
    float d = 0.f;
    for (int j = 0; j < 8; j++) d += pf[j];
    float inv = d > 0.f ? 1.f / d : 1.f;
    float wv[8];
    for (int j = 0; j < 8; j++) {
        float v = pf[j];
        for (int i = j; i < 8; i++) v *= inv;   // inv applied (8-j) times
        wv[j] = v;
    }
    if (t < 8) wfin[t] = wv[t];
    float cc = 0.f;
    if (t < NC_) for (int u = 0; u < 8; u++) cc += wv[u] * b2[u * NC_ + t];
    cconst[t] = cc;
}

// ---------------------------------------------------------------------------
// mega_prep: range-dispatched fusion of three independent prep kernels.
//  b in [0,2048):    reorder_w0  W0 -> W0r[n'][k],  n' = (n>>5)*256+u*32+(n&31)
//  b in [2048,4096): transpose_w W1 -> W1t[u][n][k]
//  b in [4096,8192): convert_x   x fp32 -> xb bf16 (8 elems/thread)
// ---------------------------------------------------------------------------
__global__ __launch_bounds__(256) void mega_prep(
    const float* __restrict__ W0, unsigned short* __restrict__ W0r,
    const float* __restrict__ W1, unsigned short* __restrict__ W1t,
    const float* __restrict__ x, unsigned short* __restrict__ xb)
{
    __shared__ float tile[32][33];
    const int b = blockIdx.x;
    if (b < 4096) {
        const int bb = b & 2047;
        const int u  = bb >> 8;
        const int n0 = (bb & 15) * 32, k0 = ((bb >> 4) & 15) * 32;
        const int tx = threadIdx.x & 31, ty = threadIdx.x >> 5;
        const float* Wb = (b < 2048 ? W0 : W1) + (long)u * 512 * 512;
#pragma unroll
        for (int i = 0; i < 4; i++)
            tile[ty + i * 8][tx] = Wb[(long)(k0 + ty + i * 8) * 512 + n0 + tx];
        __syncthreads();
        if (b < 2048) {
#pragma unroll
            for (int i = 0; i < 4; i++) {
                int n = n0 + ty + i * 8, k = k0 + tx;
                int np = (n >> 5) * 256 + u * 32 + (n & 31);
                W0r[(long)np * 512 + k] = f2bf(tile[tx][ty + i * 8]);
            }
        } else {
            unsigned short* Wo = W1t + (long)u * 512 * 512;
#pragma unroll
            for (int i = 0; i < 4; i++) {
                int n = n0 + ty + i * 8, k = k0 + tx;
                Wo[(long)n * 512 + k] = f2bf(tile[tx][ty + i * 8]);
            }
        }
    } else {
        long i = ((long)(b - 4096) * 256 + threadIdx.x) * 8;
        const float4* xp = (const float4*)(x + i);
        float4 a = xp[0], c = xp[1];
        uint4 o;
        o.x = f2bf(a.x) | ((unsigned)f2bf(a.y) << 16);
        o.y = f2bf(a.z) | ((unsigned)f2bf(a.w) << 16);
        o.z = f2bf(c.x) | ((unsigned)f2bf(c.y) << 16);
        o.w = f2bf(c.z) | ((unsigned)f2bf(c.w) << 16);
        *(uint4*)(xb + i) = o;
    }
}

// ---------------------------------------------------------------------------
// wout_build: Woutt[c][f*512+k] = sum_u wfin[u]*P2n[u,f]*W2[u][k][c]  (c<62)
// ---------------------------------------------------------------------------
__global__ __launch_bounds__(256) void wout_build(
    const float* __restrict__ W2, const float* __restrict__ P2n,
    const float* __restrict__ wfin, unsigned short* __restrict__ Woutt)
{
    const int c   = threadIdx.x & 63;
    const int row = blockIdx.x * 4 + (threadIdx.x >> 6);   // [0,4096)
    const int f = row >> 9, k = row & 511;
    float s = 0.f;
    if (c < NC_) {
#pragma unroll
        for (int u = 0; u < 8; u++)
            s += wfin[u] * P2n[u * 8 + f] * W2[((long)u * 512 + k) * NC_ + c];
    }
    Woutt[(long)c * 4096 + row] = f2bf(s);
}

// ---------------------------------------------------------------------------
// gemm0_mix (unchanged from R4): 512 threads, 128 rows x 256 cols, BK=64,
// xor-swizzled LDS, LDS mix epilogue, planar a1 with 64-B-run stores.
// ---------------------------------------------------------------------------
__global__ __launch_bounds__(512, 4) void gemm0_mix(
    const unsigned short* __restrict__ xb, const unsigned short* __restrict__ W0r,
    const float* __restrict__ b0, const float* __restrict__ P1n,
    unsigned short* __restrict__ a1, long plane)
{
    __shared__ __align__(16) unsigned short sm[128 * 264];   // 67584 B
    unsigned short* sA = sm;              // [128 rows][64] slab, xor-swizzled
    unsigned short* sB = sm + 128 * 64;   // [256 n][64]
    const int tid = threadIdx.x, w = tid >> 6, lane = tid & 63;
    const int flat = blockIdx.x;
    const int xcd = flat & 7, seq = flat >> 3;
    const int ng = xcd * 2 + (seq & 1);           // 2 n-groups per XCD
    const long mBase = (long)(seq >> 1) * 128;

    const int lr = lane >> 3;                 // row within 8-row chunk
    const int lg = (lane & 7) ^ lr;           // xor-swizzled source granule
    const int wm = w >> 2, wn = w & 3;
    const int r = lane & 15, q = lane >> 4;
    const int x7 = r & 7;

    facc acc[4][4];
#pragma unroll
    for (int i = 0; i < 4; i++)
#pragma unroll
        for (int j = 0; j < 4; j++) acc[i][j] = (facc){0.f, 0.f, 0.f, 0.f};

    for (int k0 = 0; k0 < 512; k0 += 64) {
        __syncthreads();
#pragma unroll
        for (int i = 0; i < 2; i++) {
            const int c = w + i * 8;
            gl2lds16(xb + (mBase + c * 8 + lr) * 512 + k0 + lg * 8, sA + c * 512);
        }
#pragma unroll
        for (int i = 0; i < 4; i++) {
            const int c = w * 4 + i;
            gl2lds16(W0r + ((long)ng * 256 + c * 8 + lr) * 512 + k0 + lg * 8,
                     sB + c * 512);
        }
        __syncthreads();
#pragma unroll
        for (int h = 0; h < 2; h++) {
            const int xg = ((h * 4 + q) ^ x7) * 8;
            bfrag aF[4], bF[4];
#pragma unroll
            for (int mt = 0; mt < 4; mt++)
                aF[mt] = *(const bfrag*)&sA[(wm * 64 + mt * 16 + r) * 64 + xg];
#pragma unroll
            for (int nt = 0; nt < 4; nt++)
                bF[nt] = *(const bfrag*)&sB[(wn * 64 + nt * 16 + r) * 64 + xg];
#pragma unroll
            for (int mt = 0; mt < 4; mt++)
#pragma unroll
                for (int nt = 0; nt < 4; nt++)
                    acc[mt][nt] = __builtin_amdgcn_mfma_f32_16x16x32_bf16(
                        aF[mt], bF[nt], acc[mt][nt], 0, 0, 0);
        }
    }

    __syncthreads();   // reuse sm as h0 tile [128 rows][264]
#pragma unroll
    for (int nt = 0; nt < 4; nt++) {
        const int cl = wn * 64 + nt * 16 + r;      // u = cl>>5, f = cl&31
        const float bv = b0[(cl >> 5) * 512 + ng * 32 + (cl & 31)];
#pragma unroll
        for (int mt = 0; mt < 4; mt++) {
            const int rowb = wm * 64 + mt * 16 + q * 4;
#pragma unroll
            for (int rg = 0; rg < 4; rg++) {
                float v = acc[mt][nt][rg] + bv;
                v = v > 0.f ? v : 0.f;
                sm[(rowb + rg) * 264 + cl] = f2bf(v);
            }
        }
    }
    __syncthreads();

    float pw[64];
#pragma unroll
    for (int i = 0; i < 64; i++) pw[i] = P1n[i];   // uniform -> SGPRs
    const int row = tid >> 2, fs = (tid & 3) * 8;
    float hv[8][8];
#pragma unroll
    for (int u = 0; u < 8; u++) {
        bfrag hx = *(const bfrag*)&sm[row * 264 + u * 32 + fs];
#pragma unroll
        for (int j = 0; j < 8; j++)
            hv[u][j] = bf2f((unsigned int)(unsigned short)hx[j]);
    }
    const long rowOff = (mBase + row) * 512 + ng * 32 + fs;
#pragma unroll
    for (int t = 0; t < 8; t++) {
        float o[8];
#pragma unroll
        for (int j = 0; j < 8; j++) {
            float s = 0.f;
#pragma unroll
            for (int u = 0; u < 8; u++) s = fmaf(pw[t * 8 + u], hv[u][j], s);
            o[j] = s;
        }
        uint4 ov;
        ov.x = f2bf(o[0]) | ((unsigned)f2bf(o[1]) << 16);
        ov.y = f2bf(o[2]) | ((unsigned)f2bf(o[3]) << 16);
        ov.z = f2bf(o[4]) | ((unsigned)f2bf(o[5]) << 16);
        ov.w = f2bf(o[6]) | ((unsigned)f2bf(o[7]) << 16);
        *(uint4*)(a1 + (long)t * plane + rowOff) = ov;
    }
}

// ---------------------------------------------------------------------------
// gemm_h_out v4: 512 threads, 256-row x 128-col stage-1 tile (2x the MFMA per
// barrier of v3; 2 blocks/CU = 16 waves/CU). Block = (u, nb, 256-row m-tile);
// A read once. Stage 2: LDS xor-slab round-trip (R7-verified mapping), 256x64
// out-partial vs Woutt k-slice, plane p = u*4+nb. h1 never touches HBM.
// ---------------------------------------------------------------------------
__global__ __launch_bounds__(512, 4) void gemm_h_out(
    const unsigned short* __restrict__ a1,     // planar [u][rows][512]
    const unsigned short* __restrict__ W1t,    // [u][n=512][k=512]
    const float* __restrict__ b1,
    const unsigned short* __restrict__ Woutt,  // [c=64][u*512+k]
    float* __restrict__ partial, long plane, int Bc)
{
    __shared__ __align__(16) unsigned short sm[32768];   // 64 KB
    unsigned short* sA = sm;             // [256][64]
    unsigned short* sB = sm + 16384;     // [128][64]
    unsigned short* sH = sm;             // overlay: [2 slabs][256][64]

    const int tid = threadIdx.x, w = tid >> 6, lane = tid & 63;
    const int flat = blockIdx.x;
    const int u = flat & 7;                     // consecutive blocks -> diff XCD/u
    const int nb = (flat >> 3) & 3;
    const long mBase = (long)(flat >> 5) * 256;
    const int nBase = nb * 128;

    const int lr = lane >> 3, lg = (lane & 7) ^ lr;
    const int wm = w >> 1, wn = w & 1;
    const int r = lane & 15, q = lane >> 4;
    const int x7 = r & 7;

    const unsigned short* Ab = a1 + (long)u * plane;

    // ---- stage 1: 256x128 h1 tile, K=512, A read once
    facc acc1[4][4];
#pragma unroll
    for (int i = 0; i < 4; i++)
#pragma unroll
        for (int j = 0; j < 4; j++) acc1[i][j] = (facc){0.f, 0.f, 0.f, 0.f};

    for (int k0 = 0; k0 < 512; k0 += 64) {
        __syncthreads();
#pragma unroll
        for (int i = 0; i < 4; i++) {
            const int c = w * 4 + i;                    // 0..31: A chunks
            gl2lds16(Ab + (mBase + c * 8 + lr) * 512 + k0 + lg * 8, sA + c * 512);
        }
#pragma unroll
        for (int i = 0; i < 2; i++) {
            const int c = w * 2 + i;                    // 0..15: B chunks
            gl2lds16(W1t + ((long)u * 512 + nBase + c * 8 + lr) * 512 + k0 + lg * 8,
                     sB + c * 512);
        }
        __syncthreads();
#pragma unroll
        for (int h = 0; h < 2; h++) {
            const int xg = ((h * 4 + q) ^ x7) * 8;
            bfrag aF[4], bF[4];
#pragma unroll
            for (int mt = 0; mt < 4; mt++)
                aF[mt] = *(const bfrag*)&sA[(wm * 64 + mt * 16 + r) * 64 + xg];
#pragma unroll
            for (int nt = 0; nt < 4; nt++)
                bF[nt] = *(const bfrag*)&sB[(wn * 64 + nt * 16 + r) * 64 + xg];
#pragma unroll
            for (int mt = 0; mt < 4; mt++)
#pragma unroll
                for (int nt = 0; nt < 4; nt++)
                    acc1[mt][nt] = __builtin_amdgcn_mfma_f32_16x16x32_bf16(
                        aF[mt], bF[nt], acc1[mt][nt], 0, 0, 0);
        }
    }

    __syncthreads();   // sA/sB reads done everywhere before sH overlay

    // epilogue: relu+bias -> sH xor-slab ([slab=col>>6][row 0..255][xor granule])
#pragma unroll
    for (int nt = 0; nt < 4; nt++) {
        const int col = wn * 64 + nt * 16 + r;      // [0,128)
        const float bv = b1[u * 512 + nBase + col];
        const int slab = col >> 6, cg = (col >> 3) & 7, ce = col & 7;
#pragma unroll
        for (int mt = 0; mt < 4; mt++) {
            const int rowb = wm * 64 + mt * 16 + q * 4;
#pragma unroll
            for (int rg = 0; rg < 4; rg++) {
                const int row = rowb + rg;
                float v = acc1[mt][nt][rg] + bv;
                v = v > 0.f ? v : 0.f;
                sH[slab * 16384 + row * 64 + ((cg ^ (row & 7)) * 8) + ce] = f2bf(v);
            }
        }
    }
    __syncthreads();

    // ---- stage 2: partial(256x64) = h1_tile(256x128) @ Woutt[u][nBase..+128][c]
    facc acc2[2][4];
#pragma unroll
    for (int i = 0; i < 2; i++)
#pragma unroll
        for (int j = 0; j < 4; j++) acc2[i][j] = (facc){0.f, 0.f, 0.f, 0.f};

#pragma unroll
    for (int ks = 0; ks < 4; ks++) {
        const int kh = ks >> 1, h2 = ks & 1;
        bfrag aF2[2], bF2[4];
#pragma unroll
        for (int mt = 0; mt < 2; mt++) {
            const int row = w * 32 + mt * 16 + r;   // 0..255; row&7 == x7
            aF2[mt] = *(const bfrag*)&sH[kh * 16384 + row * 64
                                         + (((h2 * 4 + q) ^ x7) * 8)];
        }
#pragma unroll
        for (int nt = 0; nt < 4; nt++) {
            const int c = nt * 16 + r;
            bF2[nt] = *(const bfrag*)(Woutt + (long)c * 4096 + u * 512
                                      + nBase + ks * 32 + q * 8);
        }
#pragma unroll
        for (int mt = 0; mt < 2; mt++)
#pragma unroll
            for (int nt = 0; nt < 4; nt++)
                acc2[mt][nt] = __builtin_amdgcn_mfma_f32_16x16x32_bf16(
                    aF2[mt], bF2[nt], acc2[mt][nt], 0, 0, 0);
    }

    // write fp32 partial plane p = u*4+nb (64-B runs)
    float* pb = partial + (((long)(u * 4 + nb)) * Bc + mBase) * 64;
#pragma unroll
    for (int nt = 0; nt < 4; nt++) {
        const int col = nt * 16 + r;
#pragma unroll
        for (int mt = 0; mt < 2; mt++) {
#pragma unroll
            for (int rg = 0; rg < 4; rg++) {
                const int row = w * 32 + mt * 16 + q * 4 + rg;
                pb[(long)row * 64 + col] = acc2[mt][nt][rg];
            }
        }
    }
}

// ---------------------------------------------------------------------------
// reduce_out: out[row][c] = sum_{p<32} partial[p][row][c] + cconst[c]
// ---------------------------------------------------------------------------
__global__ __launch_bounds__(256) void reduce_out(
    const float* __restrict__ partial, const float* __restrict__ cconst,
    float* __restrict__ out, int Bc)
{
    const long flat = (long)blockIdx.x * 256 + threadIdx.x;
    const long row = flat >> 2;
    const int cg = (int)(flat & 3) * 16;
    float s[16];
#pragma unroll
    for (int j = 0; j < 16; j++) s[j] = 0.f;
    for (int p = 0; p < 32; p++) {
        const float4* pp = (const float4*)(partial + ((long)p * Bc + row) * 64 + cg);
#pragma unroll
        for (int v4 = 0; v4 < 4; v4++) {
            float4 v = pp[v4];
            s[v4 * 4 + 0] += v.x; s[v4 * 4 + 1] += v.y;
            s[v4 * 4 + 2] += v.z; s[v4 * 4 + 3] += v.w;
        }
    }
#pragma unroll
    for (int j = 0; j < 16; j++) {
        const int c = cg + j;
        if (c < NC_) out[row * NC_ + c] = s[j] + cconst[c];
    }
}

// ---------------------------------------------------------------------------
extern "C" void kernel_launch(void* const* d_in, const int* in_sizes, int n_in,
                              void* d_out, int out_size, void* d_ws, size_t ws_size,
                              hipStream_t stream)
{
    const float* x  = (const float*)d_in[0];
    const float* p1 = (const float*)d_in[1];
    const float* p2 = (const float*)d_in[2];
    const float* pf = (const float*)d_in[3];
    const float* W0 = (const float*)d_in[4];
    const float* b0 = (const float*)d_in[5];
    const float* W1 = (const float*)d_in[6];
    const float* b1 = (const float*)d_in[7];
    const float* W2 = (const float*)d_in[8];
    const float* b2 = (const float*)d_in[9];
    float* out = (float*)d_out;

    char* ws = (char*)d_ws;
    size_t off = 0;
    auto alloc = [&](size_t bytes) -> void* {
        void* p = ws + off;
        off += (bytes + 255) & ~(size_t)255;
        return p;
    };
    float* P1n    = (float*)alloc(64 * sizeof(float));
    float* P2n    = (float*)alloc(64 * sizeof(float));
    float* wfin   = (float*)alloc(8 * sizeof(float));
    float* cconst = (float*)alloc(64 * sizeof(float));
    unsigned short* W0r   = (unsigned short*)alloc((size_t)4096 * 512 * 2);
    unsigned short* W1t   = (unsigned short*)alloc((size_t)U_ * 512 * 512 * 2);
    unsigned short* Woutt = (unsigned short*)alloc((size_t)64 * 4096 * 2);
    unsigned short* xb    = (unsigned short*)alloc((size_t)B_ * 512 * 2);

    // a1 planar (8 x Bc x 512 bf16) + fp32 partial (32 planes x Bc x 64)
    size_t remain = ws_size > off ? ws_size - off : 0;
    int Bc = 2048;
    for (int cand = B_; cand >= 2048; cand >>= 1) {
        size_t need = 8ull * cand * 512 * 2 + 32ull * cand * 64 * 4 + 1024;
        if (need <= remain) { Bc = cand; break; }
    }
    unsigned short* a1 = (unsigned short*)alloc(8ull * Bc * 512 * 2);
    float* partial     = (float*)alloc(32ull * Bc * 64 * 4);

    prep_kernel<<<1, 64, 0, stream>>>(p1, p2, pf, b2, P1n, P2n, wfin, cconst);
    mega_prep<<<dim3(8192), 256, 0, stream>>>(W0, W0r, W1, W1t, x, xb);
    wout_build<<<dim3(1024), 256, 0, stream>>>(W2, P2n, wfin, Woutt);

    const int Mb = Bc / 128;
    const int Mb2 = Bc / 256;
    const long plane = (long)Bc * 512;
    for (int bb = 0; bb < B_; bb += Bc) {
        gemm0_mix<<<dim3(16 * Mb), 512, 0, stream>>>(
            xb + (long)bb * 512, W0r, b0, P1n, a1, plane);
        gemm_h_out<<<dim3(32 * Mb2), 512, 0, stream>>>(
            a1, W1t, b1, Woutt, partial, plane, Bc);
        reduce_out<<<dim3(Bc / 64), 256, 0, stream>>>(
            partial, cconst, out + (long)bb * NC_, Bc);
    }
}